// Round 1
// baseline (338.167 us; speedup 1.0000x reference)
//
#include <hip/hip_runtime.h>

// ---------------------------------------------------------------------------
// Earth padding of 5 strips (B=1, C=256) + edge-row cross-strip convs.
// Outputs (concatenated): (256,34,364)(256,64,724)(256,184,1444)(256,64,724)(256,34,364)
// ---------------------------------------------------------------------------

struct ConvJob {
  const float* x; const float* wt; const float* bias; float* out;
  int Hin, Win, r0, Hout, Wcore, h0, type, bpr;
  // type 0: circular transposed conv (stride 2 up), Wcore = 2*Win, tile = 16 m
  // type 1: circular forward conv (stride 2 down), Wcore = Win/2, tile = 8 u
};
struct ConvJobs { ConvJob j[8]; };

// --- weight transpose: dst[(ic*5+k)*256 + oc] ---
// mode 0: src is wi  [ic][oc][1][k]   (convT weights)
// mode 1: src is wo  [oc][ic][1][k]   (fwd conv weights)
__global__ __launch_bounds__(256) void transpose_w_kernel(const float* __restrict__ src,
                                                          float* __restrict__ dst, int mode) {
  int idx = blockIdx.x * 256 + threadIdx.x;          // grid sized exactly 256*256*5
  int oc = idx & 255;
  int t = idx >> 8;
  int k = t % 5;
  int ic = t / 5;
  float v = (mode == 0) ? src[(ic * 256 + oc) * 5 + k] : src[(oc * 256 + ic) * 5 + k];
  dst[idx] = v;
}

// --- interior pad-copy: rows 2..H+1 of the padded output, circular width pad ---
__global__ __launch_bounds__(256) void pad_copy_kernel(const float* __restrict__ in,
                                                       float* __restrict__ out, int H, int W) {
  int WO4 = (W >> 2) + 1;                            // (W+4)/4
  int id = blockIdx.x * 256 + threadIdx.x;           // grid = H*WO4 blocks exactly
  int w4 = id % WO4;
  int hz = id / WO4;
  int h = hz % H;
  int c = hz / H;
  const float* src = in + ((size_t)(c * H + h)) * W;
  int wc = w4 * 4;
  float4 v;
  if (w4 >= 1 && wc <= W - 4) {
    float2 a = *(const float2*)(src + wc - 2);
    float2 b = *(const float2*)(src + wc);
    v = make_float4(a.x, a.y, b.x, b.y);
  } else {
    int c0 = wc - 2 + W;
    v.x = src[c0 % W];
    v.y = src[(c0 + 1) % W];
    v.z = src[(c0 + 2) % W];
    v.w = src[(c0 + 3) % W];
  }
  *(float4*)(out + ((size_t)(c * (H + 4) + h + 2)) * (W + 4) + wc) = v;
}

// --- zero two rows (strip0 rows 0,1; strip4 rows 32,33) ---
__global__ __launch_bounds__(256) void zero_rows_kernel(float* __restrict__ out,
                                                        int Hout, int Wout, int h0) {
  int id = blockIdx.x * 256 + threadIdx.x;
  if (id >= 256 * 2 * Wout) return;
  int w = id % Wout;
  int t = id / Wout;
  int r = t & 1;
  int c = t >> 1;
  out[((size_t)(c * Hout + h0 + r)) * Wout + w] = 0.f;
}

// --- fused edge convs: 8 jobs, thread = output channel, LDS-staged X ---
__global__ __launch_bounds__(256) void conv_all_kernel(ConvJobs js) {
  const ConvJob jb = js.j[blockIdx.y];
  int bx = blockIdx.x;
  if (bx >= 2 * jb.bpr) return;
  int tile = bx >> 1;
  int r = bx & 1;
  int t = threadIdx.x;  // oc
  __shared__ float xs[19 * 256];
  const int Win = jb.Win;
  const float* xrow = jb.x + ((size_t)(t * jb.Hin + jb.r0 + r)) * Win;
  const float* wt = jb.wt + t;
  const int Wop = jb.Wcore + 4;
  float* orow = jb.out + ((size_t)(t * jb.Hout + jb.h0 + r)) * Wop;

  if (jb.type == 1) {
    // forward: out[u] = b + sum_ic sum_k w[k] * x[(2u+k-2) mod Win], tile of 8 u
    int u0 = tile * 8;
    int cb = 2 * u0 - 2;
#pragma unroll
    for (int cc = 0; cc < 19; ++cc) {
      int col = cb + cc;
      col += (col < 0) ? Win : 0;
      col -= (col >= Win) ? Win : 0;
      xs[cc * 256 + t] = xrow[col];
    }
    __syncthreads();
    float acc[8];
    float bv = jb.bias[t];
#pragma unroll
    for (int i = 0; i < 8; ++i) acc[i] = bv;
    for (int ic0 = 0; ic0 < 256; ic0 += 4) {
      float4 xv[19];
#pragma unroll
      for (int cc = 0; cc < 19; ++cc) xv[cc] = *(const float4*)&xs[cc * 256 + ic0];
      float w[4][5];
#pragma unroll
      for (int i = 0; i < 4; ++i)
#pragma unroll
        for (int k = 0; k < 5; ++k) w[i][k] = wt[((ic0 + i) * 5 + k) * 256];
#pragma unroll
      for (int u = 0; u < 8; ++u)
#pragma unroll
        for (int k = 0; k < 5; ++k) {
          float4 xq = xv[2 * u + k];
          acc[u] += w[0][k] * xq.x + w[1][k] * xq.y + w[2][k] * xq.z + w[3][k] * xq.w;
        }
    }
#pragma unroll
    for (int i = 0; i < 8; ++i) {
      int g = u0 + i;
      float vv = acc[i];
      orow[2 + g] = vv;
      if (g < 2) orow[jb.Wcore + 2 + g] = vv;
      if (g >= jb.Wcore - 2) orow[g - (jb.Wcore - 2)] = vv;
    }
  } else {
    // transposed: out[m] = sum_ic sum_{k == m (mod 2)} w[k] * x[((m+2-k)/2) mod Win], tile of 16 m
    int m0 = tile * 16;
    int jb0 = (m0 >> 1) - 1;
#pragma unroll
    for (int cc = 0; cc < 10; ++cc) {
      int col = jb0 + cc;
      col += (col < 0) ? Win : 0;
      col -= (col >= Win) ? Win : 0;
      xs[cc * 256 + t] = xrow[col];
    }
    __syncthreads();
    float acc[16];
#pragma unroll
    for (int i = 0; i < 16; ++i) acc[i] = 0.f;
    for (int ic0 = 0; ic0 < 256; ic0 += 4) {
      float4 xv[10];
#pragma unroll
      for (int cc = 0; cc < 10; ++cc) xv[cc] = *(const float4*)&xs[cc * 256 + ic0];
      float w[4][5];
#pragma unroll
      for (int i = 0; i < 4; ++i)
#pragma unroll
        for (int k = 0; k < 5; ++k) w[i][k] = wt[((ic0 + i) * 5 + k) * 256];
#pragma unroll
      for (int ml = 0; ml < 16; ++ml) {
        if ((ml & 1) == 0) {
#pragma unroll
          for (int kk = 0; kk < 3; ++kk) {
            int k = 2 * kk;
            float4 xq = xv[(ml + 4 - k) >> 1];
            acc[ml] += w[0][k] * xq.x + w[1][k] * xq.y + w[2][k] * xq.z + w[3][k] * xq.w;
          }
        } else {
#pragma unroll
          for (int kk = 0; kk < 2; ++kk) {
            int k = 2 * kk + 1;
            float4 xq = xv[(ml + 4 - k) >> 1];
            acc[ml] += w[0][k] * xq.x + w[1][k] * xq.y + w[2][k] * xq.z + w[3][k] * xq.w;
          }
        }
      }
    }
#pragma unroll
    for (int i = 0; i < 16; ++i) {
      int g = m0 + i;
      float vv = acc[i];
      orow[2 + g] = vv;
      if (g < 2) orow[jb.Wcore + 2 + g] = vv;
      if (g >= jb.Wcore - 2) orow[g - (jb.Wcore - 2)] = vv;
    }
  }
}

extern "C" void kernel_launch(void* const* d_in, const int* in_sizes, int n_in,
                              void* d_out, int out_size, void* d_ws, size_t ws_size,
                              hipStream_t stream) {
  const float* s0 = (const float*)d_in[0];   // (256,30,360)
  const float* s1 = (const float*)d_in[1];   // (256,60,720)
  const float* s2 = (const float*)d_in[2];   // (256,180,1440)
  const float* s3 = (const float*)d_in[3];   // (256,60,720)
  const float* s4 = (const float*)d_in[4];   // (256,30,360)
  const float* wi0 = (const float*)d_in[5];  // (256,256,1,5) [ic][oc][k]
  const float* wi1 = (const float*)d_in[6];
  const float* wo0 = (const float*)d_in[7];  // (256,256,1,5) [oc][ic][k]
  const float* bo0 = (const float*)d_in[8];
  const float* wo1 = (const float*)d_in[9];
  const float* bo1 = (const float*)d_in[10];

  float* out = (float*)d_out;
  float* out0 = out;                 // (256,34,364)
  float* out1 = out + 3168256;       // (256,64,724)
  float* out2 = out + 15030272;      // (256,184,1444)
  float* out3 = out + 83048448;      // (256,64,724)
  float* out4 = out + 94910464;      // (256,34,364)

  // transposed weights in workspace: [ic][k][oc], 327680 floats each
  float* wt0 = (float*)d_ws;
  float* wt1 = wt0 + 327680;
  float* wt2 = wt1 + 327680;
  float* wt3 = wt2 + 327680;
  transpose_w_kernel<<<1280, 256, 0, stream>>>(wi0, wt0, 0);
  transpose_w_kernel<<<1280, 256, 0, stream>>>(wi1, wt1, 0);
  transpose_w_kernel<<<1280, 256, 0, stream>>>(wo0, wt2, 1);
  transpose_w_kernel<<<1280, 256, 0, stream>>>(wo1, wt3, 1);

  ConvJobs js;
  //            x   wt    bias    out   Hin  Win   r0  Hout Wcore h0   type bpr
  js.j[0] = {s1, wt0, nullptr, out2,  60,  720,  58, 184, 1440,   0, 0, 90}; // d=-1 convT -> out2 top
  js.j[1] = {s3, wt0, nullptr, out2,  60,  720,   0, 184, 1440, 182, 0, 90}; // d=+1 convT -> out2 bottom
  js.j[2] = {s0, wt1, nullptr, out1,  30,  360,  28,  64,  720,   0, 0, 45}; // convT -> out1 top
  js.j[3] = {s4, wt1, nullptr, out3,  30,  360,   0,  64,  720,  62, 0, 45}; // convT -> out3 bottom
  js.j[4] = {s2, wt2, bo0,     out1, 180, 1440,   0,  64,  720,  62, 1, 90}; // fwd  -> out1 bottom
  js.j[5] = {s2, wt2, bo0,     out3, 180, 1440, 178,  64,  720,   0, 1, 90}; // fwd  -> out3 top
  js.j[6] = {s1, wt3, bo1,     out0,  60,  720,   0,  34,  360,  32, 1, 45}; // fwd  -> out0 bottom
  js.j[7] = {s3, wt3, bo1,     out4,  60,  720,  58,  34,  360,   0, 1, 45}; // fwd  -> out4 top
  conv_all_kernel<<<dim3(180, 8), 256, 0, stream>>>(js);

  pad_copy_kernel<<<30 * 91, 256, 0, stream>>>(s0, out0, 30, 360);
  pad_copy_kernel<<<60 * 181, 256, 0, stream>>>(s1, out1, 60, 720);
  pad_copy_kernel<<<180 * 361, 256, 0, stream>>>(s2, out2, 180, 1440);
  pad_copy_kernel<<<60 * 181, 256, 0, stream>>>(s3, out3, 60, 720);
  pad_copy_kernel<<<30 * 91, 256, 0, stream>>>(s4, out4, 30, 360);

  zero_rows_kernel<<<(256 * 2 * 364 + 255) / 256, 256, 0, stream>>>(out0, 34, 364, 0);
  zero_rows_kernel<<<(256 * 2 * 364 + 255) / 256, 256, 0, stream>>>(out4, 34, 364, 32);
}